// Round 4
// baseline (115.875 us; speedup 1.0000x reference)
//
#include <hip/hip_runtime.h>
#include <hip/hip_bf16.h>
#include <stdint.h>

// PositionalSAE on MI355X — round 4.
// Barrier-FREE streaming GEMMs: each wave stages its own private 32kx16n
// W slice (2x global_load_lds), so there is no cross-wave LDS dependency and
// the K-loop has NO s_barrier. Fully unrolled 16-step loop with exact counted
// s_waitcnt vmcnt(N) per step: 3-deep stage pipeline + 2-deep A prefetch.

#define D_IN   2048
#define CHUNK  4096
#define RS     32
#define LN_EPS 1e-5f

typedef __attribute__((ext_vector_type(8))) short bf16x8;
typedef __attribute__((ext_vector_type(4))) float f32x4;

#define AS1 __attribute__((address_space(1)))
#define AS3 __attribute__((address_space(3)))

__device__ __forceinline__ void gload_lds16(const float* g, float* l) {
  __builtin_amdgcn_global_load_lds((const AS1 unsigned int*)g,
                                   (AS3 unsigned int*)l, 16, 0, 0);
}

__device__ __forceinline__ unsigned short f2bf(float f) {
  unsigned int u = __float_as_uint(f);
  u += 0x7fffu + ((u >> 16) & 1u);
  return (unsigned short)(u >> 16);
}

// Exact per-step waits (see derivation in session notes): forces stage(s)
// complete, leaves later stages + A prefetches in flight. FIFO vmcnt retire.
#define WAIT_STEP(S)                                                     \
  if ((S) == 0)       asm volatile("s_waitcnt vmcnt(8)"  ::: "memory");  \
  else if ((S) == 1)  asm volatile("s_waitcnt vmcnt(10)" ::: "memory");  \
  else if ((S) == 2)  asm volatile("s_waitcnt vmcnt(12)" ::: "memory");  \
  else if ((S) == 14) asm volatile("s_waitcnt vmcnt(8)"  ::: "memory");  \
  else if ((S) == 15) asm volatile("s_waitcnt vmcnt(4)"  ::: "memory");  \
  else                asm volatile("s_waitcnt vmcnt(10)" ::: "memory");

// ---------------------------------------------------------------------------
// Kernel 1: prep. xfrag[r][mt][kt(64)][lane(64)][8] bf16, MFMA A-frag order:
//   element j = x[m = mt*16 + (lane&15)][k = kt*32 + (lane>>4)*8 + j]
// x = acts + pos_emb[r] - b_dec. Also zeroes the 256-float LN stats.
// ---------------------------------------------------------------------------
__global__ __launch_bounds__(256) void prep_kernel(
    const float* __restrict__ acts, const float* __restrict__ pos,
    const float* __restrict__ bdec, unsigned short* __restrict__ xfrag,
    float* __restrict__ stats) {
  unsigned tid = blockIdx.x * 256u + threadIdx.x;
  if (blockIdx.x == 0) stats[threadIdx.x] = 0.0f;
  unsigned lane = tid & 63u, kt = (tid >> 6) & 63u, mt = (tid >> 12) & 1u, r = tid >> 13;
  unsigned m  = mt * 16 + (lane & 15u);
  unsigned k0 = kt * 32 + (lane >> 4) * 8;
  const float* ap = acts + (size_t)(r * RS + m) * D_IN + k0;
  const float* pp = pos  + (size_t)r * D_IN + k0;
  const float* bp = bdec + k0;
  bf16x8 v;
#pragma unroll
  for (int j = 0; j < 8; ++j) v[j] = (short)f2bf(ap[j] + pp[j] - bp[j]);
  *reinterpret_cast<bf16x8*>(xfrag + (size_t)tid * 8) = v;
}

// ---------------------------------------------------------------------------
// Kernel 2: encoder. grid = 4r x 128nt (BN=32) = 512 blocks, 8 waves
// (nsub = w>>2, kq = w&3). Per-wave private staging, no barriers in K-loop.
// ---------------------------------------------------------------------------
__global__ __launch_bounds__(512) void enc_kernel(
    const unsigned short* __restrict__ xfrag, const float* __restrict__ Wenc,
    const float* __restrict__ benc, float* __restrict__ pre,
    float* __restrict__ stats) {
  const unsigned r = blockIdx.x >> 7, nt = blockIdx.x & 127u;
  const unsigned n0 = nt * 32;
  const unsigned w = threadIdx.x >> 6, lane = threadIdx.x & 63u;
  const unsigned nsub = w >> 2, kq = w & 3u;
  const unsigned col = lane & 15u, g = lane >> 4;

  __shared__ float tiles[3 * 8 * 512];          // [buf][wave][32k x 16n], 48 KiB
  __shared__ float red[3][2][2][64][4];         // 24 KiB

  const unsigned srow = lane >> 2;              // staging row within 16-row chunk
  const float* gbase = Wenc + ((size_t)(r * D_IN + kq * 32 + srow)) * CHUNK
                            + n0 + nsub * 16 + (lane & 3u) * 4u;
  float* lbase = &tiles[w * 512];
  const unsigned short* xaL = xfrag + (size_t)r * 2 * 64 * 64 * 8 + (size_t)lane * 8;

  f32x4 acc0 = {0.f,0.f,0.f,0.f}, acc1 = acc0;
  bf16x8 aC0, aC1, aN0, aN1, aF0, aF1;

#define ENC_ST(S) { const float* gp = gbase + (size_t)(S) * 128 * CHUNK;      \
                    float* lp = lbase + ((S) % 3) * 4096;                     \
                    gload_lds16(gp, lp);                                      \
                    gload_lds16(gp + (size_t)16 * CHUNK, lp + 256); }
#define ENC_AL(S, D0, D1) {                                                   \
    const unsigned short* ap_ = xaL + (size_t)((S) * 4 + kq) * 512;           \
    D0 = *(const bf16x8*)ap_;                                                 \
    D1 = *(const bf16x8*)(ap_ + 64 * 512); }

  ENC_ST(0); ENC_ST(1); ENC_ST(2);
  asm volatile("" ::: "memory");
  ENC_AL(0, aC0, aC1);
  ENC_AL(1, aN0, aN1);
  asm volatile("" ::: "memory");

#pragma unroll
  for (int s = 0; s < 16; ++s) {
    WAIT_STEP(s);
    const float* tb = lbase + (s % 3) * 4096 + g * 128 + col;
    float bv[8];
#pragma unroll
    for (int j = 0; j < 8; ++j) bv[j] = tb[j * 16];
    asm volatile("s_waitcnt lgkmcnt(0)" ::: "memory");   // reads done before overwrite
    if (s + 3 < 16) ENC_ST(s + 3);
    asm volatile("" ::: "memory");
    if (s + 2 < 16) ENC_AL(s + 2, aF0, aF1);
    bf16x8 bfrag;
#pragma unroll
    for (int j = 0; j < 8; ++j) bfrag[j] = (short)f2bf(bv[j]);
    acc0 = __builtin_amdgcn_mfma_f32_16x16x32_bf16(aC0, bfrag, acc0, 0, 0, 0);
    acc1 = __builtin_amdgcn_mfma_f32_16x16x32_bf16(aC1, bfrag, acc1, 0, 0, 0);
    aC0 = aN0; aC1 = aN1; aN0 = aF0; aN1 = aF1;
  }

  // cross-wave reduce over kq
  if (kq != 0) {
#pragma unroll
    for (int i = 0; i < 4; ++i) {
      red[kq - 1][nsub][0][lane][i] = acc0[i];
      red[kq - 1][nsub][1][lane][i] = acc1[i];
    }
  }
  __syncthreads();
  if (kq == 0) {
    for (int q = 0; q < 3; ++q)
#pragma unroll
      for (int i = 0; i < 4; ++i) {
        acc0[i] += red[q][nsub][0][lane][i];
        acc1[i] += red[q][nsub][1][lane][i];
      }
    const unsigned nc = n0 + nsub * 16 + col;
    float bias = benc[(size_t)r * CHUNK + nc];
#pragma unroll
    for (int mt = 0; mt < 2; ++mt) {
#pragma unroll
      for (int i = 0; i < 4; ++i) {
        float v = (mt ? acc1[i] : acc0[i]) + bias;
        unsigned row = mt * 16 + g * 4 + i;
        pre[(size_t)(r * RS + row) * CHUNK + nc] = v;
        float s2 = v, q2 = v * v;
#pragma unroll
        for (int off = 1; off < 16; off <<= 1) {
          s2 += __shfl_xor(s2, off, 16);
          q2 += __shfl_xor(q2, off, 16);
        }
        if (col == 0) {
          atomicAdd(&stats[r * 32 + row], s2);
          atomicAdd(&stats[128 + r * 32 + row], q2);
        }
      }
    }
  }
}

// ---------------------------------------------------------------------------
// Kernel 3: finish LayerNorm + ReLU -> decoder A-frags bf16.
// featfrag[r][mt][kt(128)][lane][8]
// ---------------------------------------------------------------------------
__global__ __launch_bounds__(256) void lnpack_kernel(
    const float* __restrict__ pre, const float* __restrict__ stats,
    const float* __restrict__ gamma, const float* __restrict__ beta,
    unsigned short* __restrict__ featfrag) {
  unsigned tid = blockIdx.x * 256u + threadIdx.x;
  unsigned lane = tid & 63u, kt = (tid >> 6) & 127u, mt = (tid >> 13) & 1u, r = tid >> 14;
  unsigned m  = mt * 16 + (lane & 15u);
  unsigned s0 = kt * 32 + (lane >> 4) * 8;
  float mu  = stats[r * 32 + m] * (1.f / CHUNK);
  float var = stats[128 + r * 32 + m] * (1.f / CHUNK) - mu * mu;
  float rsd = rsqrtf(var + LN_EPS);
  const float* pp = pre   + (size_t)(r * RS + m) * CHUNK + s0;
  const float* gp = gamma + (size_t)r * CHUNK + s0;
  const float* bp = beta  + (size_t)r * CHUNK + s0;
  bf16x8 v;
#pragma unroll
  for (int j = 0; j < 8; ++j) {
    float x = (pp[j] - mu) * rsd * gp[j] + bp[j];
    v[j] = (short)f2bf(fmaxf(x, 0.f));
  }
  *reinterpret_cast<bf16x8*>(featfrag + (size_t)tid * 8) = v;
}

// ---------------------------------------------------------------------------
// Kernel 4: decoder. grid = 4r x 2h (K-split) x 64nt (BN=32) = 512 blocks.
// Same barrier-free per-wave pipeline; 16 steps over K'=2048. Writes part[h].
// ---------------------------------------------------------------------------
__global__ __launch_bounds__(512) void dec_kernel(
    const unsigned short* __restrict__ featfrag, const float* __restrict__ Wdec,
    float* __restrict__ part) {
  const unsigned nt = blockIdx.x & 63u, h = (blockIdx.x >> 6) & 1u, r = blockIdx.x >> 7;
  const unsigned n0 = nt * 32;
  const unsigned w = threadIdx.x >> 6, lane = threadIdx.x & 63u;
  const unsigned nsub = w >> 2, kq = w & 3u;
  const unsigned col = lane & 15u, g = lane >> 4;

  __shared__ float tiles[3 * 8 * 512];
  __shared__ float red[3][2][2][64][4];

  const unsigned srow = lane >> 2;
  const float* gbase = Wdec + ((size_t)(r * CHUNK + h * 2048 + kq * 32 + srow)) * D_IN
                            + n0 + nsub * 16 + (lane & 3u) * 4u;
  float* lbase = &tiles[w * 512];
  const unsigned short* faL = featfrag + (size_t)r * 2 * 128 * 64 * 8 + (size_t)lane * 8;

  f32x4 acc0 = {0.f,0.f,0.f,0.f}, acc1 = acc0;
  bf16x8 aC0, aC1, aN0, aN1, aF0, aF1;

#define DEC_ST(S) { const float* gp = gbase + (size_t)(S) * 128 * D_IN;       \
                    float* lp = lbase + ((S) % 3) * 4096;                     \
                    gload_lds16(gp, lp);                                      \
                    gload_lds16(gp + (size_t)16 * D_IN, lp + 256); }
#define DEC_AL(S, D0, D1) {                                                   \
    const unsigned short* ap_ = faL + (size_t)(h * 64 + (S) * 4 + kq) * 512;  \
    D0 = *(const bf16x8*)ap_;                                                 \
    D1 = *(const bf16x8*)(ap_ + 128 * 512); }

  DEC_ST(0); DEC_ST(1); DEC_ST(2);
  asm volatile("" ::: "memory");
  DEC_AL(0, aC0, aC1);
  DEC_AL(1, aN0, aN1);
  asm volatile("" ::: "memory");

#pragma unroll
  for (int s = 0; s < 16; ++s) {
    WAIT_STEP(s);
    const float* tb = lbase + (s % 3) * 4096 + g * 128 + col;
    float bv[8];
#pragma unroll
    for (int j = 0; j < 8; ++j) bv[j] = tb[j * 16];
    asm volatile("s_waitcnt lgkmcnt(0)" ::: "memory");
    if (s + 3 < 16) DEC_ST(s + 3);
    asm volatile("" ::: "memory");
    if (s + 2 < 16) DEC_AL(s + 2, aF0, aF1);
    bf16x8 bfrag;
#pragma unroll
    for (int j = 0; j < 8; ++j) bfrag[j] = (short)f2bf(bv[j]);
    acc0 = __builtin_amdgcn_mfma_f32_16x16x32_bf16(aC0, bfrag, acc0, 0, 0, 0);
    acc1 = __builtin_amdgcn_mfma_f32_16x16x32_bf16(aC1, bfrag, acc1, 0, 0, 0);
    aC0 = aN0; aC1 = aN1; aN0 = aF0; aN1 = aF1;
  }

  if (kq != 0) {
#pragma unroll
    for (int i = 0; i < 4; ++i) {
      red[kq - 1][nsub][0][lane][i] = acc0[i];
      red[kq - 1][nsub][1][lane][i] = acc1[i];
    }
  }
  __syncthreads();
  if (kq == 0) {
    for (int q = 0; q < 3; ++q)
#pragma unroll
      for (int i = 0; i < 4; ++i) {
        acc0[i] += red[q][nsub][0][lane][i];
        acc1[i] += red[q][nsub][1][lane][i];
      }
    const unsigned nc = n0 + nsub * 16 + col;
    float* pout = part + (size_t)h * 128 * D_IN;
#pragma unroll
    for (int mt = 0; mt < 2; ++mt)
#pragma unroll
      for (int i = 0; i < 4; ++i) {
        unsigned row = mt * 16 + g * 4 + i;
        pout[(size_t)(r * RS + row) * D_IN + nc] = (mt ? acc1[i] : acc0[i]);
      }
  }
}

// ---------------------------------------------------------------------------
// Kernel 5: out = part0 + part1 + b_dec (one float4 per thread).
// ---------------------------------------------------------------------------
__global__ __launch_bounds__(256) void finish_kernel(
    const float* __restrict__ part, const float* __restrict__ bdec,
    float* __restrict__ out) {
  unsigned i = blockIdx.x * 256u + threadIdx.x;
  f32x4 a = ((const f32x4*)part)[i];
  f32x4 b = ((const f32x4*)(part + 128 * D_IN))[i];
  f32x4 c = ((const f32x4*)bdec)[i & 511u];
  f32x4 o;
#pragma unroll
  for (int j = 0; j < 4; ++j) o[j] = a[j] + b[j] + c[j];
  ((f32x4*)out)[i] = o;
}

// ---------------------------------------------------------------------------
extern "C" void kernel_launch(void* const* d_in, const int* in_sizes, int n_in,
                              void* d_out, int out_size, void* d_ws, size_t ws_size,
                              hipStream_t stream) {
  const float* acts = (const float*)d_in[0];
  const float* Wenc = (const float*)d_in[1];
  const float* benc = (const float*)d_in[2];
  const float* bdec = (const float*)d_in[3];
  const float* pos  = (const float*)d_in[4];
  const float* lnw  = (const float*)d_in[5];
  const float* lnb  = (const float*)d_in[6];
  const float* Wdec = (const float*)d_in[7];
  float* out = (float*)d_out;

  char* ws = (char*)d_ws;
  float* stats            = (float*)ws;                                   // 1 KiB
  unsigned short* xfrag   = (unsigned short*)(ws + 1024);                 // 512 KiB
  float* pre              = (float*)(ws + 1024 + 512 * 1024);             // 2 MiB
  unsigned short* featfrg = (unsigned short*)(ws + 1024 + 512 * 1024 + 2 * 1024 * 1024); // 1 MiB
  float* part             = (float*)(ws + 1024 + 512 * 1024 + 3 * 1024 * 1024);          // 2 MiB

  prep_kernel  <<<128, 256, 0, stream>>>(acts, pos, bdec, xfrag, stats);
  enc_kernel   <<<512, 512, 0, stream>>>(xfrag, Wenc, benc, pre, stats);
  lnpack_kernel<<<256, 256, 0, stream>>>(pre, stats, lnw, lnb, featfrg);
  dec_kernel   <<<512, 512, 0, stream>>>(featfrg, Wdec, part);
  finish_kernel<<<256, 256, 0, stream>>>(part, bdec, out);
}

// Round 5
// 71.494 us; speedup vs baseline: 1.6208x; 1.6208x over previous
//
#include <hip/hip_runtime.h>
#include <hip/hip_bf16.h>
#include <stdint.h>

// PositionalSAE on MI355X — round 5.
// Round-2 step structure (stage-next / compute-cur / __syncthreads), but
// re-partitioned for occupancy: 256-thread blocks, 16 KB LDS, K-split GEMMs
// -> 1024 blocks = 8 blocks/CU so barrier drains overlap across blocks.
// No cross-wave reduce (each wave owns one 16x16 tile, full block-K).

#define D_IN   2048
#define CHUNK  4096
#define RS     32
#define LN_EPS 1e-5f

typedef __attribute__((ext_vector_type(8))) short bf16x8;
typedef __attribute__((ext_vector_type(4))) float f32x4;

#define AS1 __attribute__((address_space(1)))
#define AS3 __attribute__((address_space(3)))

__device__ __forceinline__ void gload_lds16(const float* g, float* l) {
  __builtin_amdgcn_global_load_lds((const AS1 unsigned int*)g,
                                   (AS3 unsigned int*)l, 16, 0, 0);
}

__device__ __forceinline__ unsigned short f2bf(float f) {
  unsigned int u = __float_as_uint(f);
  u += 0x7fffu + ((u >> 16) & 1u);
  return (unsigned short)(u >> 16);
}

// ---------------------------------------------------------------------------
// Kernel 1: prep. xfrag[r][mt][kt(64)][lane(64)][8] bf16, MFMA A-frag order:
//   element j = x[m = mt*16 + (lane&15)][k = kt*32 + (lane>>4)*8 + j]
// x = acts + pos_emb[r] - b_dec.
// ---------------------------------------------------------------------------
__global__ __launch_bounds__(256) void prep_kernel(
    const float* __restrict__ acts, const float* __restrict__ pos,
    const float* __restrict__ bdec, unsigned short* __restrict__ xfrag) {
  unsigned tid = blockIdx.x * 256u + threadIdx.x;
  unsigned lane = tid & 63u, kt = (tid >> 6) & 63u, mt = (tid >> 12) & 1u, r = tid >> 13;
  unsigned m  = mt * 16 + (lane & 15u);
  unsigned k0 = kt * 32 + (lane >> 4) * 8;
  const float* ap = acts + (size_t)(r * RS + m) * D_IN + k0;
  const float* pp = pos  + (size_t)r * D_IN + k0;
  const float* bp = bdec + k0;
  bf16x8 v;
#pragma unroll
  for (int j = 0; j < 8; ++j) v[j] = (short)f2bf(ap[j] + pp[j] - bp[j]);
  *reinterpret_cast<bf16x8*>(xfrag + (size_t)tid * 8) = v;
}

// ---------------------------------------------------------------------------
// Kernel 2: encoder. grid = 4r x 2h x 128nt = 1024 blocks, 256 thr (4 waves:
// mt = w>>1, nsub = w&1; each wave one 16x16 tile, full K'=1024).
// 16 steps of 64 k-rows; double-buffered 16 KB LDS; writes pre_part[h].
// ---------------------------------------------------------------------------
__global__ __launch_bounds__(256) void enc_kernel(
    const unsigned short* __restrict__ xfrag, const float* __restrict__ Wenc,
    float* __restrict__ pre_part) {
  const unsigned r = blockIdx.x >> 8, h = (blockIdx.x >> 7) & 1u, nt = blockIdx.x & 127u;
  const unsigned n0 = nt * 32;
  const unsigned w = threadIdx.x >> 6, lane = threadIdx.x & 63u;
  const unsigned mt = w >> 1, nsub = w & 1u;
  const unsigned col = lane & 15u, g = lane >> 4;

  __shared__ float tiles[2][64 * 32];           // 16 KiB

  const unsigned srow = lane >> 3;              // 0..7
  const unsigned scol = (lane & 7u) * 4u;       // 0..28 floats (128B rows)
  const float* gbase = Wenc + ((size_t)(r * D_IN + h * 1024)) * CHUNK + n0 + scol;
  const unsigned short* xa = xfrag + ((size_t)(r * 2 + mt) * 64) * 512 + (size_t)lane * 8;

  f32x4 acc = {0.f, 0.f, 0.f, 0.f};

  auto stageW = [&](unsigned s, unsigned b) {
#pragma unroll
    for (int l = 0; l < 2; ++l) {
      const float* gp = gbase + (size_t)(s * 64 + w * 16 + l * 8 + srow) * CHUNK;
      gload_lds16(gp, &tiles[b][(w * 2 + l) * 256]);
    }
  };

  stageW(0, 0);
  __syncthreads();

  unsigned cur = 0;
  for (unsigned s = 0; s < 16; ++s) {
    if (s + 1 < 16) stageW(s + 1, cur ^ 1);
#pragma unroll
    for (int t = 0; t < 2; ++t) {
      unsigned kt = h * 32 + s * 2 + t;
      bf16x8 a = *(const bf16x8*)(xa + (size_t)kt * 512);
      const float* tb = &tiles[cur][(t * 32 + g * 8) * 32 + nsub * 16 + col];
      bf16x8 bfrag;
#pragma unroll
      for (int j = 0; j < 8; ++j) bfrag[j] = (short)f2bf(tb[j * 32]);
      acc = __builtin_amdgcn_mfma_f32_16x16x32_bf16(a, bfrag, acc, 0, 0, 0);
    }
    __syncthreads();
    cur ^= 1;
  }

  float* pp = pre_part + (size_t)h * 128 * CHUNK;
  const unsigned nc = n0 + nsub * 16 + col;
#pragma unroll
  for (int i = 0; i < 4; ++i) {
    unsigned row = r * RS + mt * 16 + g * 4 + i;
    pp[(size_t)row * CHUNK + nc] = acc[i];
  }
}

// ---------------------------------------------------------------------------
// Kernel 3: lnpack. One block per output row (128 blocks x 256 thr).
// pre = part0 + part1 + b_enc; block-reduce mean/var; LN + ReLU; pack
// featfrag[r][mt][kt(128)][lane][8] bf16 (decoder A-frag order).
// ---------------------------------------------------------------------------
__global__ __launch_bounds__(256) void lnpack_kernel(
    const float* __restrict__ pre_part, const float* __restrict__ benc,
    const float* __restrict__ gamma, const float* __restrict__ beta,
    unsigned short* __restrict__ featfrag) {
  const unsigned row = blockIdx.x;              // 0..127
  const unsigned r = row >> 5, m = row & 31u;
  const unsigned t = threadIdx.x;               // 16 cols per thread
  const unsigned c0 = t * 16;

  const float* p0 = pre_part + (size_t)row * CHUNK + c0;
  const float* p1 = p0 + (size_t)128 * CHUNK;
  const float* bb = benc + (size_t)r * CHUNK + c0;

  float v[16];
  float s = 0.f, q = 0.f;
#pragma unroll
  for (int j = 0; j < 16; ++j) {
    v[j] = p0[j] + p1[j] + bb[j];
    s += v[j]; q += v[j] * v[j];
  }
#pragma unroll
  for (int off = 1; off < 64; off <<= 1) {
    s += __shfl_xor(s, off, 64);
    q += __shfl_xor(q, off, 64);
  }
  __shared__ float ls[4], lq[4];
  if ((t & 63u) == 0) { ls[t >> 6] = s; lq[t >> 6] = q; }
  __syncthreads();
  s = ls[0] + ls[1] + ls[2] + ls[3];
  q = lq[0] + lq[1] + lq[2] + lq[3];
  float mu  = s * (1.f / CHUNK);
  float var = q * (1.f / CHUNK) - mu * mu;
  float rsd = rsqrtf(var + LN_EPS);

  const float* gp = gamma + (size_t)r * CHUNK + c0;
  const float* bp = beta  + (size_t)r * CHUNK + c0;
  const unsigned mt = m >> 4;
#pragma unroll
  for (int half = 0; half < 2; ++half) {
    bf16x8 o;
#pragma unroll
    for (int j = 0; j < 8; ++j) {
      float x = (v[half * 8 + j] - mu) * rsd * gp[half * 8 + j] + bp[half * 8 + j];
      o[j] = (short)f2bf(fmaxf(x, 0.f));
    }
    unsigned k = c0 + half * 8;
    unsigned kt = k >> 5, grp = (k >> 3) & 3u, ln = (m & 15u) + 16u * grp;
    *(bf16x8*)(featfrag + (((size_t)(r * 2 + mt) * 128 + kt) * 64 + ln) * 8) = o;
  }
}

// ---------------------------------------------------------------------------
// Kernel 4: decoder. grid = 4r x 4h x 64nt = 1024 blocks, 256 thr (4 waves).
// K' = 1024 (16 steps of 64); writes part[h] (4 partials).
// ---------------------------------------------------------------------------
__global__ __launch_bounds__(256) void dec_kernel(
    const unsigned short* __restrict__ featfrag, const float* __restrict__ Wdec,
    float* __restrict__ part) {
  const unsigned r = blockIdx.x >> 8, h = (blockIdx.x >> 6) & 3u, nt = blockIdx.x & 63u;
  const unsigned n0 = nt * 32;
  const unsigned w = threadIdx.x >> 6, lane = threadIdx.x & 63u;
  const unsigned mt = w >> 1, nsub = w & 1u;
  const unsigned col = lane & 15u, g = lane >> 4;

  __shared__ float tiles[2][64 * 32];

  const unsigned srow = lane >> 3;
  const unsigned scol = (lane & 7u) * 4u;
  const float* gbase = Wdec + ((size_t)(r * CHUNK + h * 1024)) * D_IN + n0 + scol;
  const unsigned short* fa = featfrag + ((size_t)(r * 2 + mt) * 128) * 512 + (size_t)lane * 8;

  f32x4 acc = {0.f, 0.f, 0.f, 0.f};

  auto stageW = [&](unsigned s, unsigned b) {
#pragma unroll
    for (int l = 0; l < 2; ++l) {
      const float* gp = gbase + (size_t)(s * 64 + w * 16 + l * 8 + srow) * D_IN;
      gload_lds16(gp, &tiles[b][(w * 2 + l) * 256]);
    }
  };

  stageW(0, 0);
  __syncthreads();

  unsigned cur = 0;
  for (unsigned s = 0; s < 16; ++s) {
    if (s + 1 < 16) stageW(s + 1, cur ^ 1);
#pragma unroll
    for (int t = 0; t < 2; ++t) {
      unsigned kt = h * 32 + s * 2 + t;
      bf16x8 a = *(const bf16x8*)(fa + (size_t)kt * 512);
      const float* tb = &tiles[cur][(t * 32 + g * 8) * 32 + nsub * 16 + col];
      bf16x8 bfrag;
#pragma unroll
      for (int j = 0; j < 8; ++j) bfrag[j] = (short)f2bf(tb[j * 32]);
      acc = __builtin_amdgcn_mfma_f32_16x16x32_bf16(a, bfrag, acc, 0, 0, 0);
    }
    __syncthreads();
    cur ^= 1;
  }

  float* pp = part + (size_t)h * 128 * D_IN;
  const unsigned nc = n0 + nsub * 16 + col;
#pragma unroll
  for (int i = 0; i < 4; ++i) {
    unsigned row = r * RS + mt * 16 + g * 4 + i;
    pp[(size_t)row * D_IN + nc] = acc[i];
  }
}

// ---------------------------------------------------------------------------
// Kernel 5: out = part0+part1+part2+part3 + b_dec (one float4 per thread).
// ---------------------------------------------------------------------------
__global__ __launch_bounds__(256) void finish_kernel(
    const float* __restrict__ part, const float* __restrict__ bdec,
    float* __restrict__ out) {
  unsigned i = blockIdx.x * 256u + threadIdx.x;           // f32x4 index, 65536
  const size_t stride = (size_t)128 * D_IN / 4;
  f32x4 a0 = ((const f32x4*)part)[i];
  f32x4 a1 = ((const f32x4*)part)[i + stride];
  f32x4 a2 = ((const f32x4*)part)[i + 2 * stride];
  f32x4 a3 = ((const f32x4*)part)[i + 3 * stride];
  f32x4 c  = ((const f32x4*)bdec)[i & 511u];
  f32x4 o;
#pragma unroll
  for (int j = 0; j < 4; ++j) o[j] = a0[j] + a1[j] + a2[j] + a3[j] + c[j];
  ((f32x4*)out)[i] = o;
}

// ---------------------------------------------------------------------------
extern "C" void kernel_launch(void* const* d_in, const int* in_sizes, int n_in,
                              void* d_out, int out_size, void* d_ws, size_t ws_size,
                              hipStream_t stream) {
  const float* acts = (const float*)d_in[0];
  const float* Wenc = (const float*)d_in[1];
  const float* benc = (const float*)d_in[2];
  const float* bdec = (const float*)d_in[3];
  const float* pos  = (const float*)d_in[4];
  const float* lnw  = (const float*)d_in[5];
  const float* lnb  = (const float*)d_in[6];
  const float* Wdec = (const float*)d_in[7];
  float* out = (float*)d_out;

  char* ws = (char*)d_ws;
  unsigned short* xfrag   = (unsigned short*)ws;                          // 512 KiB
  float* pre_part         = (float*)(ws + 512 * 1024);                    // 4 MiB (2 halves)
  unsigned short* featfrg = (unsigned short*)(ws + 512 * 1024 + 4 * 1024 * 1024); // 1 MiB
  float* part             = (float*)(ws + 512 * 1024 + 5 * 1024 * 1024);  // 4 MiB (4 partials)

  prep_kernel  <<<128,  256, 0, stream>>>(acts, pos, bdec, xfrag);
  enc_kernel   <<<1024, 256, 0, stream>>>(xfrag, Wenc, pre_part);
  lnpack_kernel<<<128,  256, 0, stream>>>(pre_part, benc, lnw, lnb, featfrg);
  dec_kernel   <<<1024, 256, 0, stream>>>(featfrg, Wdec, part);
  finish_kernel<<<256,  256, 0, stream>>>(part, bdec, out);
}

// Round 7
// 66.671 us; speedup vs baseline: 1.7380x; 1.0723x over previous
//
#include <hip/hip_runtime.h>
#include <hip/hip_bf16.h>
#include <stdint.h>

// PositionalSAE on MI355X — round 7.
// Round-6 barrier-free K-loop + the missing per-wave counted vmcnt wait:
// each step issues {2 A-prefetch loads + 4 gload_lds} then waits vmcnt(6),
// draining the PREVIOUS step's stage before its ds_reads (compiler does not
// model LDS-DMA -> ds_read dependencies; the wait must be explicit).

#define D_IN   2048
#define CHUNK  4096
#define RS     32
#define LN_EPS 1e-5f

typedef __attribute__((ext_vector_type(8))) short bf16x8;
typedef __attribute__((ext_vector_type(4))) float f32x4;

#define AS1 __attribute__((address_space(1)))
#define AS3 __attribute__((address_space(3)))

__device__ __forceinline__ void gload_lds16(const float* g, float* l) {
  __builtin_amdgcn_global_load_lds((const AS1 unsigned int*)g,
                                   (AS3 unsigned int*)l, 16, 0, 0);
}

__device__ __forceinline__ unsigned short f2bf(float f) {
  unsigned int u = __float_as_uint(f);
  u += 0x7fffu + ((u >> 16) & 1u);
  return (unsigned short)(u >> 16);
}

#define MFMA16 __builtin_amdgcn_mfma_f32_16x16x32_bf16

// ---------------------------------------------------------------------------
// Kernel 1: prep. xfrag[r][mt][kt(64)][lane(64)][8] bf16, MFMA A-frag order:
//   element j = x[m = mt*16 + (lane&15)][k = kt*32 + (lane>>4)*8 + j]
// x = acts + pos_emb[r] - b_dec.
// ---------------------------------------------------------------------------
__global__ __launch_bounds__(256) void prep_kernel(
    const float* __restrict__ acts, const float* __restrict__ pos,
    const float* __restrict__ bdec, unsigned short* __restrict__ xfrag) {
  unsigned tid = blockIdx.x * 256u + threadIdx.x;
  unsigned lane = tid & 63u, kt = (tid >> 6) & 63u, mt = (tid >> 12) & 1u, r = tid >> 13;
  unsigned m  = mt * 16 + (lane & 15u);
  unsigned k0 = kt * 32 + (lane >> 4) * 8;
  const float* ap = acts + (size_t)(r * RS + m) * D_IN + k0;
  const float* pp = pos  + (size_t)r * D_IN + k0;
  const float* bp = bdec + k0;
  bf16x8 v;
#pragma unroll
  for (int j = 0; j < 8; ++j) v[j] = (short)f2bf(ap[j] + pp[j] - bp[j]);
  *reinterpret_cast<bf16x8*>(xfrag + (size_t)tid * 8) = v;
}

// ---------------------------------------------------------------------------
// Kernel 2: encoder. grid = 4r x 2h x 128nt = 1024 blocks, 256 thr (4 waves).
// Wave w owns k-rows [w*32, w*32+32) of each 128-row step (8 steps, K'=1024).
// Private double-buffered staging; NO barrier in loop; counted vmcnt(6).
// ---------------------------------------------------------------------------
__global__ __launch_bounds__(256) void enc_kernel(
    const unsigned short* __restrict__ xfrag, const float* __restrict__ Wenc,
    float* __restrict__ pre_part) {
  const unsigned r = blockIdx.x >> 8, h = (blockIdx.x >> 7) & 1u, nt = blockIdx.x & 127u;
  const unsigned n0 = nt * 32;
  const unsigned w = threadIdx.x >> 6, lane = threadIdx.x & 63u;
  const unsigned col = lane & 15u, g = lane >> 4;

  __shared__ float smem[8192];                  // 32 KiB: tiles now, red later
  float* mytile = smem + w * 2048;              // [buf][32 rows][32 cols]

  const unsigned srow = lane >> 3, scol = (lane & 7u) * 4u;
  const float* gbase = Wenc
      + ((size_t)(r * D_IN + h * 1024 + w * 32 + srow)) * CHUNK + n0 + scol;
  const unsigned short* xa0 = xfrag + ((size_t)(r * 2 + 0) * 64) * 512 + (size_t)lane * 8;
  const unsigned short* xa1 = xfrag + ((size_t)(r * 2 + 1) * 64) * 512 + (size_t)lane * 8;

  f32x4 acc00 = {0.f,0.f,0.f,0.f}, acc01 = acc00, acc10 = acc00, acc11 = acc00;

  auto stageW = [&](unsigned s, unsigned b) {
#pragma unroll
    for (int l = 0; l < 4; ++l) {
      const float* gp = gbase + (size_t)(s * 128 + l * 8) * CHUNK;
      gload_lds16(gp, mytile + b * 1024 + l * 256);
    }
  };

  bf16x8 aC0, aC1, aN0, aN1;
  {
    unsigned kt = h * 32 + w;
    aC0 = *(const bf16x8*)(xa0 + (size_t)kt * 512);
    aC1 = *(const bf16x8*)(xa1 + (size_t)kt * 512);
  }
  stageW(0, 0);

  unsigned buf = 0;
#pragma unroll
  for (int s = 0; s < 8; ++s) {
    if (s < 7) {
      unsigned kt = h * 32 + (s + 1) * 4 + w;
      aN0 = *(const bf16x8*)(xa0 + (size_t)kt * 512);
      aN1 = *(const bf16x8*)(xa1 + (size_t)kt * 512);
      stageW(s + 1, buf ^ 1);
      asm volatile("s_waitcnt vmcnt(6)" ::: "memory");   // stage(s)+A(s) done
    } else {
      asm volatile("s_waitcnt vmcnt(0)" ::: "memory");
    }
    const float* tb = mytile + buf * 1024 + g * 8 * 32 + col;
    bf16x8 b0, b1;
#pragma unroll
    for (int j = 0; j < 8; ++j) {
      b0[j] = (short)f2bf(tb[j * 32]);
      b1[j] = (short)f2bf(tb[j * 32 + 16]);
    }
    acc00 = MFMA16(aC0, b0, acc00, 0, 0, 0);
    acc01 = MFMA16(aC0, b1, acc01, 0, 0, 0);
    acc10 = MFMA16(aC1, b0, acc10, 0, 0, 0);
    acc11 = MFMA16(aC1, b1, acc11, 0, 0, 0);
    aC0 = aN0; aC1 = aN1; buf ^= 1;
  }

  __syncthreads();                              // tiles dead; smem becomes red
  float* red = smem;                            // [3][4][64][4] = 12 KiB
  if (w > 0) {
#pragma unroll
    for (int i = 0; i < 4; ++i) {
      red[(((w - 1) * 4 + 0) * 64 + lane) * 4 + i] = acc00[i];
      red[(((w - 1) * 4 + 1) * 64 + lane) * 4 + i] = acc01[i];
      red[(((w - 1) * 4 + 2) * 64 + lane) * 4 + i] = acc10[i];
      red[(((w - 1) * 4 + 3) * 64 + lane) * 4 + i] = acc11[i];
    }
  }
  __syncthreads();
  if (w == 0) {
    for (int q = 0; q < 3; ++q)
#pragma unroll
      for (int i = 0; i < 4; ++i) {
        acc00[i] += red[((q * 4 + 0) * 64 + lane) * 4 + i];
        acc01[i] += red[((q * 4 + 1) * 64 + lane) * 4 + i];
        acc10[i] += red[((q * 4 + 2) * 64 + lane) * 4 + i];
        acc11[i] += red[((q * 4 + 3) * 64 + lane) * 4 + i];
      }
    float* pp = pre_part + (size_t)h * 128 * CHUNK;
#pragma unroll
    for (int i = 0; i < 4; ++i) {
      unsigned row0 = r * RS + g * 4 + i;       // mt=0
      unsigned row1 = row0 + 16;                // mt=1
      pp[(size_t)row0 * CHUNK + n0 + col]      = acc00[i];
      pp[(size_t)row0 * CHUNK + n0 + 16 + col] = acc01[i];
      pp[(size_t)row1 * CHUNK + n0 + col]      = acc10[i];
      pp[(size_t)row1 * CHUNK + n0 + 16 + col] = acc11[i];
    }
  }
}

// ---------------------------------------------------------------------------
// Kernel 3: lnpack. One block per output row (128 blocks x 256 thr).
// pre = part0 + part1 + b_enc; block-reduce mean/var; LN + ReLU; pack
// featfrag[r][mt][kt(128)][lane][8] bf16 (decoder A-frag order).
// ---------------------------------------------------------------------------
__global__ __launch_bounds__(256) void lnpack_kernel(
    const float* __restrict__ pre_part, const float* __restrict__ benc,
    const float* __restrict__ gamma, const float* __restrict__ beta,
    unsigned short* __restrict__ featfrag) {
  const unsigned row = blockIdx.x;              // 0..127
  const unsigned r = row >> 5, m = row & 31u;
  const unsigned t = threadIdx.x;
  const unsigned c0 = t * 16;

  const float* p0 = pre_part + (size_t)row * CHUNK + c0;
  const float* p1 = p0 + (size_t)128 * CHUNK;
  const float* bb = benc + (size_t)r * CHUNK + c0;

  float v[16];
  float s = 0.f, q = 0.f;
#pragma unroll
  for (int j = 0; j < 16; ++j) {
    v[j] = p0[j] + p1[j] + bb[j];
    s += v[j]; q += v[j] * v[j];
  }
#pragma unroll
  for (int off = 1; off < 64; off <<= 1) {
    s += __shfl_xor(s, off, 64);
    q += __shfl_xor(q, off, 64);
  }
  __shared__ float ls[4], lq[4];
  if ((t & 63u) == 0) { ls[t >> 6] = s; lq[t >> 6] = q; }
  __syncthreads();
  s = ls[0] + ls[1] + ls[2] + ls[3];
  q = lq[0] + lq[1] + lq[2] + lq[3];
  float mu  = s * (1.f / CHUNK);
  float var = q * (1.f / CHUNK) - mu * mu;
  float rsd = rsqrtf(var + LN_EPS);

  const float* gp = gamma + (size_t)r * CHUNK + c0;
  const float* bp = beta  + (size_t)r * CHUNK + c0;
  const unsigned mt = m >> 4;
#pragma unroll
  for (int half = 0; half < 2; ++half) {
    bf16x8 o;
#pragma unroll
    for (int j = 0; j < 8; ++j) {
      float x = (v[half * 8 + j] - mu) * rsd * gp[half * 8 + j] + bp[half * 8 + j];
      o[j] = (short)f2bf(fmaxf(x, 0.f));
    }
    unsigned k = c0 + half * 8;
    unsigned kt = k >> 5, grp = (k >> 3) & 3u, ln = (m & 15u) + 16u * grp;
    *(bf16x8*)(featfrag + (((size_t)(r * 2 + mt) * 128 + kt) * 64 + ln) * 8) = o;
  }
}

// ---------------------------------------------------------------------------
// Kernel 4: decoder. grid = 4r x 4h x 64nt = 1024 blocks, 256 thr (4 waves).
// Same barrier-free private-slice pipeline; K'=1024 (8 steps of 128).
// Writes part[h] (4 partials).
// ---------------------------------------------------------------------------
__global__ __launch_bounds__(256) void dec_kernel(
    const unsigned short* __restrict__ featfrag, const float* __restrict__ Wdec,
    float* __restrict__ part) {
  const unsigned r = blockIdx.x >> 8, h = (blockIdx.x >> 6) & 3u, nt = blockIdx.x & 63u;
  const unsigned n0 = nt * 32;
  const unsigned w = threadIdx.x >> 6, lane = threadIdx.x & 63u;
  const unsigned col = lane & 15u, g = lane >> 4;

  __shared__ float smem[8192];
  float* mytile = smem + w * 2048;

  const unsigned srow = lane >> 3, scol = (lane & 7u) * 4u;
  const float* gbase = Wdec
      + ((size_t)(r * CHUNK + h * 1024 + w * 32 + srow)) * D_IN + n0 + scol;
  const unsigned short* fa0 = featfrag + ((size_t)(r * 2 + 0) * 128) * 512 + (size_t)lane * 8;
  const unsigned short* fa1 = featfrag + ((size_t)(r * 2 + 1) * 128) * 512 + (size_t)lane * 8;

  f32x4 acc00 = {0.f,0.f,0.f,0.f}, acc01 = acc00, acc10 = acc00, acc11 = acc00;

  auto stageW = [&](unsigned s, unsigned b) {
#pragma unroll
    for (int l = 0; l < 4; ++l) {
      const float* gp = gbase + (size_t)(s * 128 + l * 8) * D_IN;
      gload_lds16(gp, mytile + b * 1024 + l * 256);
    }
  };

  bf16x8 aC0, aC1, aN0, aN1;
  {
    unsigned kt = h * 32 + w;
    aC0 = *(const bf16x8*)(fa0 + (size_t)kt * 512);
    aC1 = *(const bf16x8*)(fa1 + (size_t)kt * 512);
  }
  stageW(0, 0);

  unsigned buf = 0;
#pragma unroll
  for (int s = 0; s < 8; ++s) {
    if (s < 7) {
      unsigned kt = h * 32 + (s + 1) * 4 + w;
      aN0 = *(const bf16x8*)(fa0 + (size_t)kt * 512);
      aN1 = *(const bf16x8*)(fa1 + (size_t)kt * 512);
      stageW(s + 1, buf ^ 1);
      asm volatile("s_waitcnt vmcnt(6)" ::: "memory");
    } else {
      asm volatile("s_waitcnt vmcnt(0)" ::: "memory");
    }
    const float* tb = mytile + buf * 1024 + g * 8 * 32 + col;
    bf16x8 b0, b1;
#pragma unroll
    for (int j = 0; j < 8; ++j) {
      b0[j] = (short)f2bf(tb[j * 32]);
      b1[j] = (short)f2bf(tb[j * 32 + 16]);
    }
    acc00 = MFMA16(aC0, b0, acc00, 0, 0, 0);
    acc01 = MFMA16(aC0, b1, acc01, 0, 0, 0);
    acc10 = MFMA16(aC1, b0, acc10, 0, 0, 0);
    acc11 = MFMA16(aC1, b1, acc11, 0, 0, 0);
    aC0 = aN0; aC1 = aN1; buf ^= 1;
  }

  __syncthreads();
  float* red = smem;
  if (w > 0) {
#pragma unroll
    for (int i = 0; i < 4; ++i) {
      red[(((w - 1) * 4 + 0) * 64 + lane) * 4 + i] = acc00[i];
      red[(((w - 1) * 4 + 1) * 64 + lane) * 4 + i] = acc01[i];
      red[(((w - 1) * 4 + 2) * 64 + lane) * 4 + i] = acc10[i];
      red[(((w - 1) * 4 + 3) * 64 + lane) * 4 + i] = acc11[i];
    }
  }
  __syncthreads();
  if (w == 0) {
    for (int q = 0; q < 3; ++q)
#pragma unroll
      for (int i = 0; i < 4; ++i) {
        acc00[i] += red[((q * 4 + 0) * 64 + lane) * 4 + i];
        acc01[i] += red[((q * 4 + 1) * 64 + lane) * 4 + i];
        acc10[i] += red[((q * 4 + 2) * 64 + lane) * 4 + i];
        acc11[i] += red[((q * 4 + 3) * 64 + lane) * 4 + i];
      }
    float* pp = part + (size_t)h * 128 * D_IN;
#pragma unroll
    for (int i = 0; i < 4; ++i) {
      unsigned row0 = r * RS + g * 4 + i;
      unsigned row1 = row0 + 16;
      pp[(size_t)row0 * D_IN + n0 + col]      = acc00[i];
      pp[(size_t)row0 * D_IN + n0 + 16 + col] = acc01[i];
      pp[(size_t)row1 * D_IN + n0 + col]      = acc10[i];
      pp[(size_t)row1 * D_IN + n0 + 16 + col] = acc11[i];
    }
  }
}

// ---------------------------------------------------------------------------
// Kernel 5: out = part0+part1+part2+part3 + b_dec (one float4 per thread).
// ---------------------------------------------------------------------------
__global__ __launch_bounds__(256) void finish_kernel(
    const float* __restrict__ part, const float* __restrict__ bdec,
    float* __restrict__ out) {
  unsigned i = blockIdx.x * 256u + threadIdx.x;
  const size_t stride = (size_t)128 * D_IN / 4;
  f32x4 a0 = ((const f32x4*)part)[i];
  f32x4 a1 = ((const f32x4*)part)[i + stride];
  f32x4 a2 = ((const f32x4*)part)[i + 2 * stride];
  f32x4 a3 = ((const f32x4*)part)[i + 3 * stride];
  f32x4 c  = ((const f32x4*)bdec)[i & 511u];
  f32x4 o;
#pragma unroll
  for (int j = 0; j < 4; ++j) o[j] = a0[j] + a1[j] + a2[j] + a3[j] + c[j];
  ((f32x4*)out)[i] = o;
}

// ---------------------------------------------------------------------------
extern "C" void kernel_launch(void* const* d_in, const int* in_sizes, int n_in,
                              void* d_out, int out_size, void* d_ws, size_t ws_size,
                              hipStream_t stream) {
  const float* acts = (const float*)d_in[0];
  const float* Wenc = (const float*)d_in[1];
  const float* benc = (const float*)d_in[2];
  const float* bdec = (const float*)d_in[3];
  const float* pos  = (const float*)d_in[4];
  const float* lnw  = (const float*)d_in[5];
  const float* lnb  = (const float*)d_in[6];
  const float* Wdec = (const float*)d_in[7];
  float* out = (float*)d_out;

  char* ws = (char*)d_ws;
  unsigned short* xfrag   = (unsigned short*)ws;                          // 512 KiB
  float* pre_part         = (float*)(ws + 512 * 1024);                    // 4 MiB (2 halves)
  unsigned short* featfrg = (unsigned short*)(ws + 512 * 1024 + 4 * 1024 * 1024); // 1 MiB
  float* part             = (float*)(ws + 512 * 1024 + 5 * 1024 * 1024);  // 4 MiB (4 partials)

  prep_kernel  <<<128,  256, 0, stream>>>(acts, pos, bdec, xfrag);
  enc_kernel   <<<1024, 256, 0, stream>>>(xfrag, Wenc, pre_part);
  lnpack_kernel<<<128,  256, 0, stream>>>(pre_part, benc, lnw, lnb, featfrg);
  dec_kernel   <<<1024, 256, 0, stream>>>(featfrg, Wdec, part);
  finish_kernel<<<256,  256, 0, stream>>>(part, bdec, out);
}